// Round 5
// baseline (236.382 us; speedup 1.0000x reference)
//
#include <hip/hip_runtime.h>
#include <hip/hip_bf16.h>

// ---------------------------------------------------------------------------
// WaveletNauralNet: 9-level DWT -> 8 band reconstructions (h: 2048x32768,
// linear in x1) -> relu -> W0 (181x32768) -> relu -> W1 (13x181) -> relu ->
// W2 (10x13).
//   K1 (THIS ROUND - FUSED): one block per row computes analysis d1..d9 in
//       LDS (exact dwt2 + LOFF packing, global D drain DELETED) and then all
//       8 band reconstructions in-block:
//         L2/3/4: barrier-free register fins (R4-verified numerics)
//         L5..L9: R1-verified initpair/pair/final cascades, d read from LDS
//       Eliminates the 34MB D write + ~20MB D fetch + one kernel launch.
//       LDS 48.3KB -> 3 blocks/CU, launch_bounds(256,3).
//       W0 fp32->fp16 cvt stays fused (blocks >= 2048).
//   K2: BM=256 split-K MFMA GEMM, counted-vmcnt double-buffer pipeline
//       (R4 form: stage(ks+1) -> vmcnt(7) -> s_barrier -> MFMA -> s_barrier).
//   K3: reduce partials + MLP layers 1..2 (R8 form)
// ---------------------------------------------------------------------------

typedef _Float16 f16x8 __attribute__((ext_vector_type(8)));
typedef _Float16 f16x4v __attribute__((ext_vector_type(4)));
typedef float f32x4 __attribute__((ext_vector_type(4)));

#define WV_THREADS 256
#define NSPLIT 32
#define KCHUNK 1024
#define GEMM_BM 256

// reconstruction filters
#define L0 0.23037781330885523f
#define L1 0.7148465705525415f
#define L2f 0.6308807679295904f
#define L3 -0.02798376941698385f
#define L4 -0.18703481171888114f
#define L5 0.030841381835986965f
#define L6 0.032883011666982945f
#define L7 -0.010597401784997278f

#define H0 -0.010597401784997278f
#define H1 -0.032883011666982945f
#define H2 0.030841381835986965f
#define H3 0.18703481171888114f
#define H4 -0.02798376941698385f
#define H5 -0.6308807679295904f
#define H6 0.7148465705525415f
#define H7 -0.23037781330885523f

// a/d lengths per level; LOFF = in-LDS d packing (lev even -> r1, odd -> r2)
__constant__ constexpr int cNL[10] = {4096, 2051, 1029, 518, 262, 134, 70, 38, 22, 14};
// d2@r1+1036 d3@r2+520 d4@r1+2068 d5@r2+1040 d6@r1+2332 d7@r2+1176
// d8@r1+2404 d9@r2+1216  (all multiples of 4 -> 16B-aligned float4 reads)

__device__ __forceinline__ int ext_idx(int j, int n) {
  return (j < 6) ? (5 - j) : ((j < n + 6) ? (j - 6) : (2 * n + 5 - j));
}

// one DWT level, 2 outputs per thread, stride-1 lanes. (unchanged)
__device__ __forceinline__ void dwt2(const float* a, float* anext, float* d,
                                     int n, int m, bool store_a) {
  const int ng = (m + 1) >> 1;
  for (int g = threadIdx.x; g < ng; g += WV_THREADS) {
    float w[10];
    if (g >= 2 && 4 * g + 9 <= n + 5) {
      const float2* af = (const float2*)a + (2 * g - 3);
      float2 b0 = af[0], b1 = af[1], b2 = af[2], b3 = af[3], b4 = af[4];
      w[0] = b0.x; w[1] = b0.y; w[2] = b1.x; w[3] = b1.y; w[4] = b2.x;
      w[5] = b2.y; w[6] = b3.x; w[7] = b3.y; w[8] = b4.x; w[9] = b4.y;
    } else {
#pragma unroll
      for (int q = 0; q < 10; ++q) {
        int j = 4 * g + q;
        int jm = n + 12;
        if (j > jm) j = jm;
        w[q] = a[ext_idx(j, n)];
      }
    }
    float sl0 = w[0]*L0 + w[1]*L1 + w[2]*L2f + w[3]*L3 + w[4]*L4 + w[5]*L5 + w[6]*L6 + w[7]*L7;
    float sh0 = w[0]*H0 + w[1]*H1 + w[2]*H2  + w[3]*H3 + w[4]*H4 + w[5]*H5 + w[6]*H6 + w[7]*H7;
    float sl1 = w[2]*L0 + w[3]*L1 + w[4]*L2f + w[5]*L3 + w[6]*L4 + w[7]*L5 + w[8]*L6 + w[9]*L7;
    float sh1 = w[2]*H0 + w[3]*H1 + w[4]*H2  + w[5]*H3 + w[6]*H4 + w[7]*H5 + w[8]*H6 + w[9]*H7;
    if (2 * g + 1 < m) {
      if (store_a) *(float2*)(anext + 2 * g) = make_float2(sl0, sl1);
      *(float2*)(d + 2 * g) = make_float2(sh0, sh1);
    } else {
      if (store_a) anext[2 * g] = sl0;
      d[2 * g] = sh0;
    }
  }
}

// ---------------------------------------------------------------------------
// Swizzled LDS float4 slot accessors: slot u -> u ^ ((u>>3)&7). Bijective
// within each aligned 8-slot (128B) row; conflict-free b128 reads/writes.
#define SWZ(u) ((u) ^ (((u) >> 3) & 7))
__device__ __forceinline__ const float4* lds4c(const float* b, int s) {
  return (const float4*)b + SWZ(s);
}
__device__ __forceinline__ float4* lds4(float* b, int s) {
  return (float4*)b + SWZ(s);
}

// ---------------------------------------------------------------------------
// IDWT level primitives (register arrays, fully unrolled).
template <int NP>
__device__ __forceinline__ void lvlL(const float* a, float* v) {  // nocd
#pragma unroll
  for (int q = 0; q < NP; ++q) {
    v[2*q]   = a[q+3]*L0 + a[q+2]*L2f + a[q+1]*L4 + a[q]*L6;
    v[2*q+1] = a[q+3]*L1 + a[q+2]*L3  + a[q+1]*L5 + a[q]*L7;
  }
}
template <int NP>
__device__ __forceinline__ void lvlH(const float* d, float* v) {  // init (cd only)
#pragma unroll
  for (int q = 0; q < NP; ++q) {
    v[2*q]   = d[q+3]*H0 + d[q+2]*H2 + d[q+1]*H4 + d[q]*H6;
    v[2*q+1] = d[q+3]*H1 + d[q+2]*H3 + d[q+1]*H5 + d[q]*H7;
  }
}
template <int NP>
__device__ __forceinline__ void lvlLH(const float* a, const float* d, float* v) {  // withcd
#pragma unroll
  for (int q = 0; q < NP; ++q) {
    v[2*q]   = a[q+3]*L0 + a[q+2]*L2f + a[q+1]*L4 + a[q]*L6
             + d[q+3]*H0 + d[q+2]*H2  + d[q+1]*H4 + d[q]*H6;
    v[2*q+1] = a[q+3]*L1 + a[q+2]*L3  + a[q+1]*L5 + a[q]*L7
             + d[q+3]*H1 + d[q+2]*H3  + d[q+1]*H5 + d[q]*H7;
  }
}

// LDS window readers (bases 16B/8B aligned; over-reads land in-bounds, and
// their garbage only feeds lanes whose outputs are never stored -- same
// property the old global pads had, verified by R1/R4 passes)
__device__ __forceinline__ void g8f2(const float* p, int s, float* w) {  // s even
#pragma unroll
  for (int i = 0; i < 4; ++i) {
    float2 v = *(const float2*)(p + s + 2 * i);
    w[2*i] = v.x; w[2*i+1] = v.y;
  }
}
__device__ __forceinline__ void g12f4(const float* p, int s, float* w) {  // s%4==0
#pragma unroll
  for (int i = 0; i < 3; ++i) {
    float4 v = *(const float4*)(p + s + 4 * i);
    w[4*i] = v.x; w[4*i+1] = v.y; w[4*i+2] = v.z; w[4*i+3] = v.w;
  }
}

// relu + f16 store of 16 interleaved e/o values
__device__ __forceinline__ void store16(_Float16* outg, int t, const float* v) {
  f16x8 h0, h1;
#pragma unroll
  for (int i = 0; i < 8; ++i) h0[i] = (_Float16)fmaxf(v[i], 0.f);
#pragma unroll
  for (int i = 0; i < 8; ++i) h1[i] = (_Float16)fmaxf(v[8 + i], 0.f);
  *(f16x8*)(outg + 16 * t) = h0;
  *(f16x8*)(outg + 16 * t + 8) = h1;
}

// ---------------------------------------------------------------------------
// Single-stage register fins for L2/L3/L4 (no LDS scratch, no barrier).
__device__ __forceinline__ void fin2(const float* d2, const float* d1, _Float16* og) {
  const int t = threadIdx.x;
  float dw[12];  g12f4(d2, 4 * t, dw);
  float mid[12]; lvlH<6>(dw, mid);           // 2052-arr vals [8t, 8t+12)
  float d1w[12]; g12f4(d1, 8 * t, d1w);
  float v[16];   lvlLH<8>(mid, d1w, v);      // final with cd = d1
  store16(og, t, v);
}

__device__ __forceinline__ void fin3(const float* d3, const float* d2, _Float16* og) {
  const int t = threadIdx.x;
  float dw[8];   g8f2(d3, 2 * t, dw);
  float v0[10];  lvlH<5>(dw, v0);            // init vals [4t, 4t+10)
  float d2w[12]; g12f4(d2, 4 * t, d2w);
  float v1[12];  lvlLH<6>(v0, d2w, v1);      // wc vals [8t, 8t+12)
  float v[16];   lvlL<8>(v1, v);
  store16(og, t, v);
}

__device__ __forceinline__ void fin4(const float* d4, const float* d3, _Float16* og) {
  const int t = threadIdx.x;
  float dw[7];
#pragma unroll
  for (int i = 0; i < 7; ++i) dw[i] = d4[t + i];
  float v0[8];   lvlH<4>(dw, v0);            // [2t, 2t+8)
  float d3w[8];  g8f2(d3, 2 * t, d3w);
  float v1[10];  lvlLH<5>(v0, d3w, v1);      // [4t, 4t+10)
  float v2[12];  lvlL<6>(v1, v2);            // [8t, 8t+12)
  float v[16];   lvlL<8>(v2, v);
  store16(og, t, v);
}

// ---------------------------------------------------------------------------
// R1-verified multi-stage machinery for L5..L9 (d now from LDS).
template <bool FINAL, int N>
__device__ __forceinline__ void stepL(const float* ca, float* outl, _Float16* outg) {
  constexpr int npair = N - 3;
  constexpr int ng = (npair + 7) >> 3;
  const int t = threadIdx.x;
  if (t >= ng) return;
  float w[12];
  float4 a = *lds4c(ca, 2 * t), b = *lds4c(ca, 2 * t + 1), c = *lds4c(ca, 2 * t + 2);
  w[0]=a.x; w[1]=a.y; w[2]=a.z; w[3]=a.w; w[4]=b.x; w[5]=b.y; w[6]=b.z; w[7]=b.w;
  w[8]=c.x; w[9]=c.y; w[10]=c.z; w[11]=c.w;
  float v[16]; lvlL<8>(w, v);
  if constexpr (FINAL) {
    store16(outg, t, v);
  } else {
#pragma unroll
    for (int j = 0; j < 4; ++j) {
      const int p2 = 8 * t + 2 * j;
      if (p2 + 1 < npair) {
        *lds4(outl, 4 * t + j) = make_float4(v[4*j], v[4*j+1], v[4*j+2], v[4*j+3]);
      } else if (p2 < npair) {
        *(float2*)lds4(outl, 4 * t + j) = make_float2(v[4*j], v[4*j+1]);
      }
    }
  }
}

// Two fused no-cd stages from a 12-float window.
__device__ __forceinline__ void nocd2_core(const float w[12], float r[11],
                                           float E[8], float O[8]) {
#pragma unroll
  for (int h = 0; h < 6; ++h) {
    float e = w[h+3]*L0 + w[h+2]*L2f + w[h+1]*L4 + w[h]*L6;
    float o = w[h+3]*L1 + w[h+2]*L3  + w[h+1]*L5 + w[h]*L7;
    r[2*h] = e;
    if (2*h + 1 < 11) r[2*h+1] = o;
  }
#pragma unroll
  for (int pp = 0; pp < 8; ++pp) {
    E[pp] = r[pp+3]*L0 + r[pp+2]*L2f + r[pp+1]*L4 + r[pp]*L6;
    O[pp] = r[pp+3]*L1 + r[pp+2]*L3  + r[pp+1]*L5 + r[pp]*L7;
  }
}

// PAIR: two no-cd IDWT steps fused, LDS -> LDS.
template <int N1>
__device__ __forceinline__ void pair16(const float* cur, float* outl) {
  constexpr int N2 = (2 * N1 - 6 == 1030) ? 1029 : (2 * N1 - 6);
  constexpr int np2 = N2 - 3;
  constexpr int ng = (np2 + 7) >> 3;
  const int t = threadIdx.x;
  if (t >= ng) return;
  float w[12];
  float4 a = *lds4c(cur, t), b = *lds4c(cur, t + 1), c = *lds4c(cur, t + 2);
  w[0]=a.x; w[1]=a.y; w[2]=a.z; w[3]=a.w; w[4]=b.x; w[5]=b.y; w[6]=b.z; w[7]=b.w;
  w[8]=c.x; w[9]=c.y; w[10]=c.z; w[11]=c.w;
  float r[11], E[8], O[8];
  nocd2_core(w, r, E, O);
#pragma unroll
  for (int j = 0; j < 4; ++j) {
    const int p2 = 8 * t + 2 * j;
    if (p2 + 1 < np2) {
      *lds4(outl, 4 * t + j) = make_float4(E[2*j], O[2*j], E[2*j+1], O[2*j+1]);
    } else if (p2 < np2) {
      *(float2*)lds4(outl, 4 * t + j) = make_float2(E[2*j], O[2*j]);
    }
  }
}

// FINPAIR: no-cd stage (input len 1029) fused with the final stage.
__device__ __forceinline__ void finpair16(const float* cur, _Float16* outg) {
  const int t = threadIdx.x;
  float w[12];
  float4 a = *lds4c(cur, t), b = *lds4c(cur, t + 1), c = *lds4c(cur, t + 2);
  w[0]=a.x; w[1]=a.y; w[2]=a.z; w[3]=a.w; w[4]=b.x; w[5]=b.y; w[6]=b.z; w[7]=b.w;
  w[8]=c.x; w[9]=c.y; w[10]=c.z; w[11]=c.w;
  float r[11], E[8], O[8];
  nocd2_core(w, r, E, O);
  float vv[16];
#pragma unroll
  for (int q = 0; q < 8; ++q) { vv[2*q] = E[q]; vv[2*q+1] = O[q]; }
  store16(outg, t, vv);
}

// INITPAIR: init (d_L via H) fused with the with-cd stage (d_{L-1}); LDS in.
template <int NL, int NLm1>
__device__ __forceinline__ void initpair16(const float* cdL, const float* cdm,
                                           float* outl) {
  constexpr int np2 = NLm1 - 3;
  constexpr int ng = (np2 + 7) >> 3;
  const int t = threadIdx.x;
  if (t >= ng) return;
  float w[12]; g12f4(cdL, 4 * t, w);
  float r[11];
#pragma unroll
  for (int h = 0; h < 6; ++h) {
    float e = w[h+3]*H0 + w[h+2]*H2 + w[h+1]*H4 + w[h]*H6;
    float o = w[h+3]*H1 + w[h+2]*H3 + w[h+1]*H5 + w[h]*H7;
    r[2*h] = e;
    if (2*h + 1 < 11) r[2*h+1] = o;
  }
  float v[12]; g12f4(cdm, 8 * t, v);
  float E[8], O[8];
#pragma unroll
  for (int pp = 0; pp < 8; ++pp) {
    E[pp] = r[pp+3]*L0 + r[pp+2]*L2f + r[pp+1]*L4 + r[pp]*L6
          + v[pp+3]*H0 + v[pp+2]*H2  + v[pp+1]*H4 + v[pp]*H6;
    O[pp] = r[pp+3]*L1 + r[pp+2]*L3  + r[pp+1]*L5 + r[pp]*L7
          + v[pp+3]*H1 + v[pp+2]*H3  + v[pp+1]*H5 + v[pp]*H7;
  }
#pragma unroll
  for (int j = 0; j < 4; ++j) {
    const int p2 = 8 * t + 2 * j;
    if (p2 + 1 < np2) {
      *lds4(outl, 4 * t + j) = make_float4(E[2*j], O[2*j], E[2*j+1], O[2*j+1]);
    } else if (p2 < np2) {
      *(float2*)lds4(outl, 4 * t + j) = make_float2(E[2*j], O[2*j]);
    }
  }
}

// ---------------------------------------------------------------------------
// FUSED: blocks [0,2048) = full per-row analysis+synthesis (D in LDS only);
// blocks [2048, 2048+6144) = W0 fp32->fp16 convert.
__global__ __launch_bounds__(WV_THREADS, 3) void wv_row_cvt(
    const float* __restrict__ x, _Float16* __restrict__ A,
    const float* __restrict__ W0, _Float16* __restrict__ Bw) {
  __shared__ alignas(16) float r1[4104];
  __shared__ alignas(16) float r2[2056];
  __shared__ alignas(16) float d1b[2052];
  __shared__ alignas(16) float s1[2080];
  __shared__ alignas(16) float s2[2080];
  const int tid = threadIdx.x;

  if (blockIdx.x >= 2048) {  // ---- cvt path ----
    size_t i = ((size_t)(blockIdx.x - 2048) * 256 + tid) * 4;
    int rowc = (int)(i >> 15);
    f16x4v h;
    if (rowc < 181) {
      const float4 v = *(const float4*)(W0 + i);
      h[0] = (_Float16)v.x; h[1] = (_Float16)v.y;
      h[2] = (_Float16)v.z; h[3] = (_Float16)v.w;
    } else {
      h[0] = (_Float16)0.f; h[1] = (_Float16)0.f;
      h[2] = (_Float16)0.f; h[3] = (_Float16)0.f;
    }
    *(f16x4v*)(Bw + i) = h;
    return;
  }

  const int NLa[10]  = {4096, 2051, 1029, 518, 262, 134, 70, 38, 22, 14};
  const int LOFF[10] = {0, 0, 1036, 520, 2068, 1040, 2332, 1176, 2404, 1216};
  const int row = blockIdx.x;

  // ---- analysis: x -> d1..d9, all in LDS ----
  const float4* xr = (const float4*)(x + (size_t)row * 4096);
  for (int i = tid; i < 1024; i += WV_THREADS) ((float4*)r1)[i] = xr[i];
  __syncthreads();

  dwt2(r1, r2, d1b, NLa[0], NLa[1], true);   // d1 -> LDS (was global)
  __syncthreads();
  const float* ap = r2;
  float* an = r1;
  for (int lev = 2; lev <= 9; ++lev) {
    float* dbuf = ((lev & 1) ? r2 : r1) + LOFF[lev];
    dwt2(ap, an, dbuf, NLa[lev - 1], NLa[lev], lev < 9);
    __syncthreads();
    const float* t = ap; ap = an; an = (float*)t;
  }
  // d homes (stable, read-only from here):
  const float* d2 = r1 + 1036;  const float* d3 = r2 + 520;
  const float* d4 = r1 + 2068;  const float* d5 = r2 + 1040;
  const float* d6 = r1 + 2332;  const float* d7 = r2 + 1176;
  const float* d8 = r1 + 2404;  const float* d9 = r2 + 1216;

  _Float16* og = A + (size_t)row * 32768;

  // ---- bands L2..L4: barrier-free fins ----
  fin2(d2, d1b, og);
  fin3(d3, d2, og + 4096);
  fin4(d4, d3, og + 8192);

  // ---- bands L5..L9: cascades (s1/s2 scratch; barriers also order the
  //      previous band's s-buffer reads before this band's writes) ----
  // L5
  initpair16<cNL[5], cNL[4]>(d5, d4, s1);
  __syncthreads();
  pair16<518>(s1, s2); __syncthreads();
  stepL<true, 2051>(s2, nullptr, og + 3 * 4096);
  // L6
  initpair16<cNL[6], cNL[5]>(d6, d5, s1);
  __syncthreads();
  pair16<262>(s1, s2); __syncthreads();
  finpair16(s2, og + 4 * 4096);
  // L7
  initpair16<cNL[7], cNL[6]>(d7, d6, s1);
  __syncthreads();
  pair16<134>(s1, s2); __syncthreads();
  pair16<518>(s2, s1); __syncthreads();
  stepL<true, 2051>(s1, nullptr, og + 5 * 4096);
  // L8
  initpair16<cNL[8], cNL[7]>(d8, d7, s1);
  __syncthreads();
  pair16<70>(s1, s2); __syncthreads();
  pair16<262>(s2, s1); __syncthreads();
  finpair16(s1, og + 6 * 4096);
  // L9
  initpair16<cNL[9], cNL[8]>(d9, d8, s1);
  __syncthreads();
  pair16<38>(s1, s2); __syncthreads();
  pair16<134>(s2, s1); __syncthreads();
  pair16<518>(s1, s2); __syncthreads();
  stepL<true, 2051>(s2, nullptr, og + 7 * 4096);
}

// ---------------------------------------------------------------------------
__device__ __forceinline__ void load_lds16(const void* g, void* l) {
  __builtin_amdgcn_global_load_lds((__attribute__((address_space(1))) unsigned int*)g,
                                   (__attribute__((address_space(3))) unsigned int*)l,
                                   16, 0, 0);
}

// C(2048x192) += A(2048x32768,f16) * Bw(192x32768,f16)^T, fp32 split-K
// partials. BM=256, 8 waves, grid (8 m, 32 k) = 256 blocks = 1/CU.
// Counted-vmcnt double-buffer pipeline (R4 form).
__global__ __launch_bounds__(512, 2) void gemm_kernel(
    const _Float16* __restrict__ A, const _Float16* __restrict__ Bw,
    float* __restrict__ P) {
  __shared__ _Float16 As[2][GEMM_BM * 64];  // 2 x 32 KB
  __shared__ _Float16 Bs[2][192 * 64];      // 2 x 24 KB  (total 112 KB)
  const int tid = threadIdx.x;
  const int lane = tid & 63;
  const int wave = tid >> 6;          // 0..7
  const int m0 = blockIdx.x * GEMM_BM;
  const int k_idx = blockIdx.y;
  const int k0 = k_idx * KCHUNK;

  f32x4 acc[2][12];
#pragma unroll
  for (int mt = 0; mt < 2; ++mt)
#pragma unroll
    for (int nt = 0; nt < 12; ++nt) acc[mt][nt] = (f32x4){0.f, 0.f, 0.f, 0.f};

  auto stage = [&](int ks, int b) {
    const int kbase = k0 + (ks << 6);
#pragma unroll
    for (int t = 0; t < 4; ++t) {
      int c = wave * 4 + t;
      int g = (c << 6) + lane;
      int r = g >> 3, cs = g & 7;
      const _Float16* gp = A + (size_t)(m0 + r) * 32768 + kbase + ((cs ^ (r & 7)) << 3);
      load_lds16(gp, (char*)As[b] + ((size_t)c << 10));
    }
#pragma unroll
    for (int t = 0; t < 3; ++t) {
      int c = wave * 3 + t;
      int g = (c << 6) + lane;
      int r = g >> 3, cs = g & 7;
      const _Float16* gp = Bw + (size_t)r * 32768 + kbase + ((cs ^ (r & 7)) << 3);
      load_lds16(gp, (char*)Bs[b] + ((size_t)c << 10));
    }
  };

  auto compute = [&](int cur) {
#pragma unroll
    for (int kk = 0; kk < 2; ++kk) {
      const int chunk = kk * 4 + (lane >> 4);
      f16x8 af[2];
#pragma unroll
      for (int mt = 0; mt < 2; ++mt) {
        int r = wave * 32 + mt * 16 + (lane & 15);
        af[mt] = *(const f16x8*)(As[cur] + r * 64 + ((chunk ^ (r & 7)) << 3));
      }
#pragma unroll
      for (int nt = 0; nt < 12; ++nt) {
        int rb = nt * 16 + (lane & 15);
        f16x8 bf = *(const f16x8*)(Bs[cur] + rb * 64 + ((chunk ^ (rb & 7)) << 3));
        acc[0][nt] = __builtin_amdgcn_mfma_f32_16x16x32_f16(af[0], bf, acc[0][nt], 0, 0, 0);
        acc[1][nt] = __builtin_amdgcn_mfma_f32_16x16x32_f16(af[1], bf, acc[1][nt], 0, 0, 0);
      }
    }
  };

  constexpr int NT = KCHUNK >> 6;   // 16 tiles
  stage(0, 0);
  for (int ks = 0; ks < NT - 1; ++ks) {
    stage(ks + 1, (ks + 1) & 1);
    asm volatile("s_waitcnt vmcnt(7)" ::: "memory");  // tile ks resident
    __builtin_amdgcn_s_barrier();
    compute(ks & 1);
    __builtin_amdgcn_s_barrier();
  }
  asm volatile("s_waitcnt vmcnt(0)" ::: "memory");
  __builtin_amdgcn_s_barrier();
  compute((NT - 1) & 1);

  float* Pp = P + ((size_t)k_idx * 2048 + m0) * 192;
#pragma unroll
  for (int mt = 0; mt < 2; ++mt)
#pragma unroll
    for (int nt = 0; nt < 12; ++nt)
#pragma unroll
      for (int r4 = 0; r4 < 4; ++r4) {
        int rr = wave * 32 + mt * 16 + ((lane >> 4) << 2) + r4;
        int cc = nt * 16 + (lane & 15);
        Pp[(size_t)rr * 192 + cc] = acc[mt][nt][r4];
      }
}

// ---------------------------------------------------------------------------
// P reduce: 4 wave-groups x 8 splits, coalesced; then layers 1..2. (R8 form.)
__global__ __launch_bounds__(256) void mlp_kernel(
    const float* __restrict__ P, const float* __restrict__ b0,
    const float* __restrict__ W1, const float* __restrict__ b1,
    const float* __restrict__ W2, const float* __restrict__ b2,
    float* __restrict__ out) {
  __shared__ float part[4][193];
  __shared__ float h1[192];
  __shared__ float h2[13];
  const int row = blockIdx.x;
  const int t = threadIdx.x;
  const int g = t >> 6;
  const int l = t & 63;

  float a0 = 0.f, a1 = 0.f, a2 = 0.f;
  for (int si = 0; si < NSPLIT / 4; ++si) {
    int s = g + (si << 2);
    const float* Pr = P + ((size_t)s * 2048 + row) * 192;
    a0 += Pr[l]; a1 += Pr[64 + l]; a2 += Pr[128 + l];
  }
  part[g][l] = a0; part[g][64 + l] = a1; part[g][128 + l] = a2;
  __syncthreads();

  if (t < 192) {
    float v = part[0][t] + part[1][t] + part[2][t] + part[3][t];
    h1[t] = (t < 181) ? fmaxf(v + b0[t], 0.f) : 0.f;
  }
  __syncthreads();

#pragma unroll
  for (int r = 0; r < 4; ++r) {
    int j = g + (r << 2);
    if (j < 13) {
      float v = 0.f;
#pragma unroll
      for (int q = 0; q < 3; ++q) {
        int n = l + (q << 6);
        if (n < 181) v += h1[n] * W1[j * 181 + n];
      }
      for (int off = 32; off >= 1; off >>= 1) v += __shfl_down(v, off);
      if (l == 0) h2[j] = fmaxf(v + b1[j], 0.f);
    }
  }
  __syncthreads();

  if (t < 10) {
    float c = b2[t];
#pragma unroll
    for (int j = 0; j < 13; ++j) c += h2[j] * W2[t * 13 + j];
    out[(size_t)row * 10 + t] = c;
  }
}

// ---------------------------------------------------------------------------
extern "C" void kernel_launch(void* const* d_in, const int* in_sizes, int n_in,
                              void* d_out, int out_size, void* d_ws, size_t ws_size,
                              hipStream_t stream) {
  const float* x1 = (const float*)d_in[0];
  const float* W0 = (const float*)d_in[3];
  const float* b0 = (const float*)d_in[4];
  const float* W1 = (const float*)d_in[5];
  const float* b1 = (const float*)d_in[6];
  const float* W2 = (const float*)d_in[7];
  const float* b2 = (const float*)d_in[8];
  float* out = (float*)d_out;

  char* ws = (char*)d_ws;
  const size_t A_BYTES = (size_t)2048 * 32768 * 2;
  const size_t B_BYTES = (size_t)192 * 32768 * 2;
  _Float16* Afeat = (_Float16*)ws;
  _Float16* Bw = (_Float16*)(ws + A_BYTES);
  float* P = (float*)(ws + A_BYTES + B_BYTES);

  wv_row_cvt<<<2048 + 6144, WV_THREADS, 0, stream>>>(x1, Afeat, W0, Bw);
  dim3 gg(2048 / GEMM_BM, NSPLIT);
  gemm_kernel<<<gg, 512, 0, stream>>>(Afeat, Bw, P);
  mlp_kernel<<<2048, 256, 0, stream>>>(P, b0, W1, b1, W2, b2, out);
}